// Round 3
// baseline (886.347 us; speedup 1.0000x reference)
//
#include <hip/hip_runtime.h>
#include <hip/hip_bf16.h>

#define HID 512
#define NH  8
#define DD  64
#define GG  64
#define EPSF 1e-5f

typedef __attribute__((ext_vector_type(8))) short short8;
typedef __attribute__((ext_vector_type(4))) float floatx4;

__device__ __forceinline__ short f2bf(float f) {
    union { float f; unsigned u; } v; v.f = f;
    unsigned r = v.u + 0x7fffu + ((v.u >> 16) & 1u);
    return (short)(r >> 16);
}
__device__ __forceinline__ float bf2f(short s) {
    union { unsigned u; float f; } v;
    v.u = ((unsigned)(unsigned short)s) << 16;
    return v.f;
}

#define GLOAD_LDS16(g, l) __builtin_amdgcn_global_load_lds( \
    (const __attribute__((address_space(1))) unsigned int*)(g), \
    (__attribute__((address_space(3))) unsigned int*)(l), 16, 0, 0)

// ---------------------------------------------------------------------------
// cast x (f32) -> x_bf (bf16), 8 elems/thread
// ---------------------------------------------------------------------------
__global__ __launch_bounds__(256)
void cast_kernel(const float* __restrict__ x, short* __restrict__ xb, int n8) {
    int i = blockIdx.x * 256 + threadIdx.x;
    if (i >= n8) return;
    const float4* p = (const float4*)(x + (size_t)i * 8);
    float4 a = p[0], b = p[1];
    short8 v;
    v[0] = f2bf(a.x); v[1] = f2bf(a.y); v[2] = f2bf(a.z); v[3] = f2bf(a.w);
    v[4] = f2bf(b.x); v[5] = f2bf(b.y); v[6] = f2bf(b.z); v[7] = f2bf(b.w);
    *(short8*)(xb + (size_t)i * 8) = v;
}

// ---------------------------------------------------------------------------
// fold1: Wcat (1024x512 bf16) = [Wfx ; temp[h] * (Ws @ Wx_head)]
//        bias_cat (1024 f32)  = [bfx ; temp[h] * (Ws @ bx_head + bs)]
// ---------------------------------------------------------------------------
__global__ void fold1_kernel(const float* __restrict__ Wx, const float* __restrict__ bx,
                             const float* __restrict__ Wfx, const float* __restrict__ bfx,
                             const float* __restrict__ Ws, const float* __restrict__ bs,
                             const float* __restrict__ temp,
                             short* __restrict__ Wcat, float* __restrict__ bias_cat) {
    int idx = blockIdx.x * 256 + threadIdx.x;   // 0 .. 1024*512-1
    int row = idx >> 9;
    int k = idx & 511;
    float val;
    if (row < 512) {
        val = Wfx[row * 512 + k];
        if (k == 0) bias_cat[row] = bfx[row];
    } else {
        int hg = row - 512;
        int h = hg >> 6, g = hg & 63;
        float t = temp[h];
        float s = 0.f;
        #pragma unroll 8
        for (int d = 0; d < 64; ++d) s += Ws[g * 64 + d] * Wx[(h * 64 + d) * 512 + k];
        val = s * t;
        if (k == 0) {
            float b = 0.f;
            for (int d = 0; d < 64; ++d) b += Ws[g * 64 + d] * bx[h * 64 + d];
            bias_cat[row] = (b + bs[g]) * t;
        }
    }
    Wcat[idx] = f2bf(val);
}

// ---------------------------------------------------------------------------
// gemm256p: PERSISTENT 256x256 / BK=64 / 8-wave / 8-phase counted-vmcnt GEMM.
// C(M x ncols) = A(M x 512) @ B(ncols x 512)^T + bias.
//
// grid = 256 blocks exactly (1/CU, 128 KiB LDS). Block (xcd=bid&7, q=bid>>3)
// keeps col-tile cb = q%CB for its whole life (B panel + bias stay L2-hot)
// and walks row-tiles rt = xcd*RperX + q/CB + t*(32/CB). The phase schedule
// is SEAMLESS across units: u==3's phases (which previously idled + drained)
// stage the next unit's K0/K1 from Anext. One vmcnt(0) per block lifetime.
//
// A-READ tile index is clamped to Rtiles-1 (phantom tile on the last XCD
// reads a valid tile instead of past the buffer; its stores remain fully
// masked by grow < M).
//
// Seam liveness: prev-q7 vmcnt(6) drains thru q4 => buf0/K0 landed before the
// new unit's q0 ds_reads; new-q3 vmcnt(6) drains prev-q5..q7 + q0 => buf1/K1
// landed before q4. Epilogue stores only inflate vmcnt (in-order retirement
// => waits become conservative, still correct).
// ---------------------------------------------------------------------------
template <bool OUT_F32, bool FUSE_SM, int CB>
__global__ __launch_bounds__(512, 2)
void gemm256p(const short* __restrict__ A, int lda,
              const short* __restrict__ B,           // (ncols x 512) bf16 row-major
              const float* __restrict__ bias,
              void* __restrict__ Cp, int ldc,
              int M, int RperX, int Rtiles) {
    __shared__ short As[2][256 * 64];
    __shared__ short Bs[2][256 * 64];

    const int bid = blockIdx.x;                 // 0..255
    const int xcd = bid & 7;
    const int q_  = bid >> 3;                   // 0..31 (CU within XCD)
    const int cb  = q_ % CB;                    // constant col-tile per block
    const int u0  = q_ / CB;                    // first local row-tile
    const int STEP = 32 / CB;
    const int cnt = (RperX - u0 + STEP - 1) / STEP;   // units this block owns
    if (cnt <= 0) return;

    const int tid = threadIdx.x;
    const int wid = tid >> 6;
    const int lane = tid & 63;
    const int wm = wid >> 2, wn = wid & 3;      // 2 x 4 wave grid
    const int lr = lane & 15, lq = lane >> 4;
    const int col0 = cb * 256;

    // staging: one gload_lds covers 64 rows; pre-swizzled source chunk so
    // LDS[row][pch] = G[row][pch ^ (row&7)] while dest stays linear.
    const int srow = tid >> 3;                  // 0..63
    const int schunk = (tid & 7) ^ (srow & 7);
    const short* Bsrc = B + (size_t)(col0 + srow) * lda + schunk * 8;
    int rt = xcd * RperX + u0;                  // current row-tile index (store)
    const int soff = srow * lda + schunk * 8;   // per-thread read offset
    const short* Ac = A + (size_t)min(rt, Rtiles - 1) * 256 * lda + soff;
    const int ldst = wid * 512;                 // wave-uniform dest (shorts)

#define GA(buf, base, kt, Lk) GLOAD_LDS16((base) + (size_t)((Lk) * 64) * lda + (kt) * 64, \
                                          &As[buf][(Lk) * 4096 + ldst])
#define GB(buf, kt, Lk) GLOAD_LDS16(Bsrc + (size_t)((Lk) * 64) * lda + (kt) * 64, \
                                    &Bs[buf][(Lk) * 4096 + ldst])

    // frag read offsets (row&7 == lr&7 for all frag rows since 16 ≡ 0 mod 8)
    const int axor = lr & 7;
    const int coff0 = (lq ^ axor) * 8;
    const int coff1 = ((4 + lq) ^ axor) * 8;
    const int aoff = (wm * 128 + lr) * 64;
    const int boff = (wn * 64 + lr) * 64;

    // bias is constant per block (cb fixed): load once, no vmcnt pollution later
    float bcol[4];
    #pragma unroll
    for (int j = 0; j < 4; ++j) bcol[j] = bias[col0 + wn * 64 + j * 16 + lr];
    const bool do_sm = FUSE_SM && (cb >= CB / 2);

    floatx4 acc[8][4];
    #pragma unroll
    for (int i = 0; i < 8; ++i)
        #pragma unroll
        for (int j = 0; j < 4; ++j) acc[i][j] = (floatx4)(0.f);

    // prologue (unit 0): K0 complete (8 loads) + K1 all-but-A-L1L3 (6 loads)
    GA(0, Ac, 0, 0); GA(0, Ac, 0, 1); GA(0, Ac, 0, 2); GA(0, Ac, 0, 3);
    GB(0, 0, 0); GB(0, 0, 1); GB(0, 0, 2); GB(0, 0, 3);
    GB(1, 1, 0); GB(1, 1, 1); GB(1, 1, 2); GB(1, 1, 3);
    GA(1, Ac, 1, 0); GA(1, Ac, 1, 2);
    asm volatile("s_waitcnt vmcnt(6)" ::: "memory");   // K0 landed
    __builtin_amdgcn_s_barrier();

    short8 bfr[4][2];
    short8 af[2][2];

    #pragma unroll 1
    for (int t = 0; t < cnt; ++t) {
        const short* An = (t + 1 < cnt)
            ? (A + (size_t)min(rt + STEP, Rtiles - 1) * 256 * lda + soff)
            : Ac;                                // clamp at tail

        #pragma unroll 1
        for (int u = 0; u < 4; ++u) {
            const short* Au = (u == 3) ? An : Ac;
            const int ku1 = 2 * u + 1;
            const int kt2 = (2 * u + 2) & 7, kt3 = (2 * u + 3) & 7;
            #pragma unroll
            for (int cbuf = 0; cbuf < 2; ++cbuf) {     // K-tile 2u+cbuf in buf cbuf
                #pragma unroll
                for (int p = 0; p < 4; ++p) {
                    const int q = cbuf * 4 + p;
                    // --- ds-loads for this phase ---
                    if (p == 0) {
                        #pragma unroll
                        for (int j = 0; j < 4; ++j) {
                            bfr[j][0] = *(const short8*)&Bs[cbuf][boff + j * 1024 + coff0];
                            bfr[j][1] = *(const short8*)&Bs[cbuf][boff + j * 1024 + coff1];
                        }
                    }
                    #pragma unroll
                    for (int i2 = 0; i2 < 2; ++i2) {
                        af[i2][0] = *(const short8*)&As[cbuf][aoff + (2 * p + i2) * 1024 + coff0];
                        af[i2][1] = *(const short8*)&As[cbuf][aoff + (2 * p + i2) * 1024 + coff1];
                    }
                    // --- stage one half-tile (2 gload_lds); u==3 stages NEXT unit ---
                    if (q == 0)      { GA(1, Ac, ku1, 1); GA(1, Ac, ku1, 3); }
                    else if (q == 1) { GB(0, kt2, 0); GB(0, kt2, 1); }
                    else if (q == 2) { GB(0, kt2, 2); GB(0, kt2, 3); }
                    else if (q == 3) { GA(0, Au, kt2, 0); GA(0, Au, kt2, 2); }
                    else if (q == 4) { GA(0, Au, kt2, 1); GA(0, Au, kt2, 3); }
                    else if (q == 5) { GB(1, kt3, 0); GB(1, kt3, 1); }
                    else if (q == 6) { GB(1, kt3, 2); GB(1, kt3, 3); }
                    else             { GA(1, Au, kt3, 0); GA(1, Au, kt3, 2); }
                    // --- counted vmcnt once per K-tile (T4); never 0 in-loop ---
                    if (q == 3 || q == 7)
                        asm volatile("s_waitcnt vmcnt(6)" ::: "memory");
                    __builtin_amdgcn_s_barrier();
                    __builtin_amdgcn_s_setprio(1);
                    #pragma unroll
                    for (int ks = 0; ks < 2; ++ks)
                        #pragma unroll
                        for (int i2 = 0; i2 < 2; ++i2)
                            #pragma unroll
                            for (int j = 0; j < 4; ++j)
                                acc[2 * p + i2][j] = __builtin_amdgcn_mfma_f32_16x16x32_bf16(
                                    af[i2][ks], bfr[j][ks], acc[2 * p + i2][j], 0, 0, 0);
                    __builtin_amdgcn_s_setprio(0);
                    __builtin_amdgcn_s_barrier();
                }
            }
        }

        // --- per-unit epilogue: next unit's K0/K1 loads already in flight ---
        const int row0 = rt * 256;
        #pragma unroll
        for (int i = 0; i < 8; ++i) {
            #pragma unroll
            for (int r = 0; r < 4; ++r) {
                const int grow = row0 + wm * 128 + i * 16 + lq * 4 + r;
                float v[4];
                #pragma unroll
                for (int j = 0; j < 4; ++j) v[j] = acc[i][j][r] + bcol[j];
                if (do_sm) {
                    float m = fmaxf(fmaxf(v[0], v[1]), fmaxf(v[2], v[3]));
                    #pragma unroll
                    for (int off = 1; off < 16; off <<= 1) m = fmaxf(m, __shfl_xor(m, off));
                    float sum = 0.f;
                    #pragma unroll
                    for (int j = 0; j < 4; ++j) { v[j] = __expf(v[j] - m); sum += v[j]; }
                    #pragma unroll
                    for (int off = 1; off < 16; off <<= 1) sum += __shfl_xor(sum, off);
                    const float inv = 1.f / sum;
                    #pragma unroll
                    for (int j = 0; j < 4; ++j) v[j] *= inv;
                }
                if (grow < M) {
                    #pragma unroll
                    for (int j = 0; j < 4; ++j) {
                        const int gcol = col0 + wn * 64 + j * 16 + lr;
                        if constexpr (OUT_F32) ((float*)Cp)[(size_t)grow * ldc + gcol] = v[j];
                        else                   ((short*)Cp)[(size_t)grow * ldc + gcol] = f2bf(v[j]);
                    }
                }
            }
        }
        // reset accumulators for next unit
        #pragma unroll
        for (int i = 0; i < 8; ++i)
            #pragma unroll
            for (int j = 0; j < 4; ++j) acc[i][j] = (floatx4)(0.f);

        Ac = An;
        rt += STEP;
    }
#undef GA
#undef GB
    // drain all outstanding lds-DMA / stores / ds ops before endpgm
    asm volatile("s_waitcnt vmcnt(0) lgkmcnt(0)" ::: "memory");
}

// ---------------------------------------------------------------------------
// pool_mfma: tok_raw[h,g,d] += sum_n w[n,h,g]*fx[n,h,d]; norm[h,g] += sum_n w
// (unchanged)
// ---------------------------------------------------------------------------
__global__ __launch_bounds__(256)
void pool_mfma(const short* __restrict__ mid, float* __restrict__ tok_raw,
               float* __restrict__ norm, int N, int chunk) {
    const int h = blockIdx.y;
    const int n0 = blockIdx.x * chunk;
    if (n0 >= N) return;
    const int ksteps = (min(chunk, N - n0)) >> 5;

    const int tid = threadIdx.x;
    const int wid = tid >> 6, lane = tid & 63;
    const int lr = lane & 15, lq = lane >> 4;
    const int wg = (wid >> 1) * 32, wd = (wid & 1) * 32;

    __shared__ short wt[32 * 72];
    __shared__ short ft[32 * 72];

    const int sn = tid >> 3;
    const int sc0 = (tid & 7) * 8;
    const int scr = (sc0 + 16 * ((sn >> 3) & 3)) & 63;
    const int st_off = sn * 72 + scr;

    const int ra = ((wg + lr) + 16 * lq) & 63;
    const int rb = ((wd + lr) + 16 * lq) & 63;

    const short* wbase = mid + (size_t)n0 * 1024 + 512 + h * 64;
    const short* fbase = mid + (size_t)n0 * 1024 + h * 64;

    floatx4 acc[2][2];
    #pragma unroll
    for (int i = 0; i < 2; ++i)
        #pragma unroll
        for (int j = 0; j < 2; ++j) acc[i][j] = (floatx4)(0.f);
    floatx4 accn[2];
    accn[0] = (floatx4)(0.f); accn[1] = (floatx4)(0.f);

    short8 ones;
    #pragma unroll
    for (int j = 0; j < 8; ++j) ones[j] = (short)0x3F80;

    for (int ks = 0; ks < ksteps; ++ks) {
        const size_t roff = (size_t)(ks * 32 + sn) * 1024;
        short8 wv = *(const short8*)(wbase + roff + sc0);
        short8 fv = *(const short8*)(fbase + roff + sc0);
        __syncthreads();
        *(short8*)&wt[st_off] = wv;
        *(short8*)&ft[st_off] = fv;
        __syncthreads();

        short8 af[2], bf_[2];
        #pragma unroll
        for (int i = 0; i < 2; ++i) {
            short tmpv[8];
            #pragma unroll
            for (int j = 0; j < 8; ++j)
                tmpv[j] = wt[(lq * 8 + j) * 72 + ((ra + i * 16) & 63)];
            af[i] = *(const short8*)tmpv;
        }
        #pragma unroll
        for (int j2 = 0; j2 < 2; ++j2) {
            short tmpv[8];
            #pragma unroll
            for (int j = 0; j < 8; ++j)
                tmpv[j] = ft[(lq * 8 + j) * 72 + ((rb + j2 * 16) & 63)];
            bf_[j2] = *(const short8*)tmpv;
        }
        #pragma unroll
        for (int i = 0; i < 2; ++i)
            #pragma unroll
            for (int j = 0; j < 2; ++j)
                acc[i][j] = __builtin_amdgcn_mfma_f32_16x16x32_bf16(af[i], bf_[j], acc[i][j], 0, 0, 0);
        if (wd == 0) {
            #pragma unroll
            for (int i = 0; i < 2; ++i)
                accn[i] = __builtin_amdgcn_mfma_f32_16x16x32_bf16(af[i], ones, accn[i], 0, 0, 0);
        }
    }

    #pragma unroll
    for (int i = 0; i < 2; ++i) {
        #pragma unroll
        for (int r = 0; r < 4; ++r) {
            int g = wg + i * 16 + lq * 4 + r;
            #pragma unroll
            for (int j = 0; j < 2; ++j) {
                int d = wd + j * 16 + lr;
                atomicAdd(&tok_raw[(h * 64 + g) * 64 + d], acc[i][j][r]);
            }
        }
    }
    if (wd == 0 && lr == 0) {
        #pragma unroll
        for (int i = 0; i < 2; ++i)
            #pragma unroll
            for (int r = 0; r < 4; ++r)
                atomicAdd(&norm[h * 64 + wg + i * 16 + lq * 4 + r], accn[i][r]);
    }
}

// ---------------------------------------------------------------------------
// attn: per head, G=64 tokens (unchanged)
// ---------------------------------------------------------------------------
__global__ __launch_bounds__(256)
void attn_kernel(const float* __restrict__ tok_raw, const float* __restrict__ norm,
                 const float* __restrict__ Wq, const float* __restrict__ Wk,
                 const float* __restrict__ Wv, const float* __restrict__ Wo,
                 float* __restrict__ out_tok) {
    const int h = blockIdx.x;
    const int tid = threadIdx.x;
    const int g = tid & 63, part = tid >> 6;
    const int o0 = part * 16;

    __shared__ float tk[64][65];
    __shared__ float qq[64][65];
    __shared__ float kk[64][65];
    __shared__ float vv[64][65];
    __shared__ float pp[64][65];
    __shared__ float od[64][65];

    const float inv = 1.f / (norm[h * 64 + g] + EPSF);
    #pragma unroll
    for (int dd = 0; dd < 16; ++dd) {
        int d = o0 + dd;
        tk[g][d] = tok_raw[(size_t)(h * 64 + g) * 64 + d] * inv;
    }
    __syncthreads();

    float t[64];
    #pragma unroll
    for (int d = 0; d < 64; ++d) t[d] = tk[g][d];
    #pragma unroll
    for (int oo = 0; oo < 16; ++oo) {
        int o = o0 + oo;
        float sq = 0.f, sk = 0.f, sv = 0.f;
        #pragma unroll
        for (int d = 0; d < 64; ++d) {
            float td = t[d];
            sq += td * Wq[o * 64 + d];
            sk += td * Wk[o * 64 + d];
            sv += td * Wv[o * 64 + d];
        }
        qq[g][o] = sq; kk[g][o] = sk; vv[g][o] = sv;
    }
    __syncthreads();

    float q[64];
    #pragma unroll
    for (int o = 0; o < 64; ++o) q[o] = qq[g][o];
    #pragma unroll
    for (int jj = 0; jj < 16; ++jj) {
        int j = o0 + jj;
        float s = 0.f;
        #pragma unroll
        for (int o = 0; o < 64; ++o) s += q[o] * kk[j][o];
        pp[g][j] = s * 0.125f;
    }
    __syncthreads();

    float sr[64];
    float mx = -1e30f;
    #pragma unroll
    for (int j = 0; j < 64; ++j) { sr[j] = pp[g][j]; mx = fmaxf(mx, sr[j]); }
    float sum = 0.f;
    #pragma unroll
    for (int j = 0; j < 64; ++j) { sr[j] = __expf(sr[j] - mx); sum += sr[j]; }
    const float isum = 1.f / sum;

    #pragma unroll
    for (int dd = 0; dd < 16; ++dd) {
        int d = o0 + dd;
        float a = 0.f;
        #pragma unroll
        for (int j = 0; j < 64; ++j) a += sr[j] * vv[j][d];
        od[g][d] = a * isum;
    }
    __syncthreads();

    float ot[64];
    #pragma unroll
    for (int d = 0; d < 64; ++d) ot[d] = od[g][d];
    #pragma unroll
    for (int oo = 0; oo < 16; ++oo) {
        int o = o0 + oo;
        float a = 0.f;
        #pragma unroll
        for (int d = 0; d < 64; ++d) a += ot[d] * Wo[o * 64 + d];
        out_tok[(size_t)(h * 64 + g) * 64 + o] = a;
    }
}

// ---------------------------------------------------------------------------
// fold2: V[o, h*64+g] = sum_d out_tok[h,g,d] * Wout[o, h*64+d]  (bf16 out)
// ---------------------------------------------------------------------------
__global__ void fold2_kernel(const float* __restrict__ out_tok,
                             const float* __restrict__ Wout, short* __restrict__ Vbf) {
    int idx = blockIdx.x * 256 + threadIdx.x;
    int o = idx >> 9, hg = idx & 511;
    int h = hg >> 6;
    const float* ot = out_tok + (size_t)hg * 64;
    const float* wo = Wout + (size_t)o * 512 + h * 64;
    float s = 0.f;
    #pragma unroll 8
    for (int d = 0; d < 64; ++d) s += ot[d] * wo[d];
    Vbf[idx] = f2bf(s);
}

// ---------------------------------------------------------------------------
extern "C" void kernel_launch(void* const* d_in, const int* in_sizes, int n_in,
                              void* d_out, int out_size, void* d_ws, size_t ws_size,
                              hipStream_t stream) {
    const float* x    = (const float*)d_in[0];
    const float* Wx   = (const float*)d_in[1];
    const float* bx   = (const float*)d_in[2];
    const float* Wfx  = (const float*)d_in[3];
    const float* bfx  = (const float*)d_in[4];
    const float* Ws   = (const float*)d_in[5];
    const float* bs   = (const float*)d_in[6];
    const float* temp = (const float*)d_in[7];
    const float* Wq   = (const float*)d_in[8];
    const float* Wk   = (const float*)d_in[9];
    const float* Wv   = (const float*)d_in[10];
    const float* Wo   = (const float*)d_in[11];
    const float* Wout = (const float*)d_in[12];
    const float* bout = (const float*)d_in[13];

    const int N = in_sizes[0] / HID;

    char* p = (char*)d_ws;
    short* mid = (short*)p;           p += (size_t)N * 1024 * 2;       // fx | w (bf16)
    short* Wcat = (short*)p;          p += (size_t)1024 * 512 * 2;
    float* bias_cat = (float*)p;      p += 1024 * 4;
    float* tok_raw = (float*)p;       p += (size_t)NH * GG * DD * 4;   // contiguous with norm
    float* norm_ = (float*)p;         p += (size_t)NH * GG * 4;
    float* out_tok = (float*)p;       p += (size_t)NH * GG * DD * 4;
    short* Vbf = (short*)p;           p += (size_t)512 * 512 * 2;
    short* x_bf = (short*)d_out;     // d_out (N*512 f32) hosts x_bf until GEMM2

    cast_kernel<<<(N * 512 / 8 + 255) / 256, 256, 0, stream>>>(x, x_bf, N * 512 / 8);
    fold1_kernel<<<2048, 256, 0, stream>>>(Wx, bx, Wfx, bfx, Ws, bs, temp, Wcat, bias_cat);

    const int R = (N + 255) / 256;       // 391 row-tiles
    const int RperX = (R + 7) / 8;       // 49 per XCD

    // GEMM1: persistent, 4 col tiles of 256, fused softmax on logits half
    gemm256p<false, true, 4><<<256, 512, 0, stream>>>(
        x_bf, HID, Wcat, bias_cat, (void*)mid, 1024, N, RperX, R);

    hipMemsetAsync(tok_raw, 0, (size_t)(NH * GG * DD + NH * GG) * 4, stream);

    // pool: split-K MFMA; chunk multiple of 32 (N=100000 is a multiple of 32)
    const int chunk = 544;                       // 17 k-steps per block
    dim3 g2((N + chunk - 1) / chunk, 8);
    pool_mfma<<<g2, 256, 0, stream>>>(mid, tok_raw, norm_, N, chunk);

    attn_kernel<<<8, 256, 0, stream>>>(tok_raw, norm_, Wq, Wk, Wv, Wo, out_tok);

    fold2_kernel<<<1024, 256, 0, stream>>>(out_tok, Wout, Vbf);

    // GEMM2: persistent, 2 col tiles of 256 (A = w half of mid; output f32 + bout)
    gemm256p<true, false, 2><<<256, 512, 0, stream>>>(
        mid + 512, 1024, Vbf, bout, d_out, HID, N, RperX, R);
}

// Round 4
// 847.494 us; speedup vs baseline: 1.0458x; 1.0458x over previous
//
#include <hip/hip_runtime.h>
#include <hip/hip_bf16.h>

#define HID 512
#define NH  8
#define DD  64
#define GG  64
#define EPSF 1e-5f

typedef __attribute__((ext_vector_type(8))) short short8;
typedef __attribute__((ext_vector_type(4))) short short4v;
typedef __attribute__((ext_vector_type(4))) float floatx4;

__device__ __forceinline__ short f2bf(float f) {
    union { float f; unsigned u; } v; v.f = f;
    unsigned r = v.u + 0x7fffu + ((v.u >> 16) & 1u);
    return (short)(r >> 16);
}
__device__ __forceinline__ float bf2f(short s) {
    union { unsigned u; float f; } v;
    v.u = ((unsigned)(unsigned short)s) << 16;
    return v.f;
}

#define GLOAD_LDS16(g, l) __builtin_amdgcn_global_load_lds( \
    (const __attribute__((address_space(1))) unsigned int*)(g), \
    (__attribute__((address_space(3))) unsigned int*)(l), 16, 0, 0)

// ---------------------------------------------------------------------------
// cast x (f32) -> x_bf (bf16), 8 elems/thread
// ---------------------------------------------------------------------------
__global__ __launch_bounds__(256)
void cast_kernel(const float* __restrict__ x, short* __restrict__ xb, int n8) {
    int i = blockIdx.x * 256 + threadIdx.x;
    if (i >= n8) return;
    const float4* p = (const float4*)(x + (size_t)i * 8);
    float4 a = p[0], b = p[1];
    short8 v;
    v[0] = f2bf(a.x); v[1] = f2bf(a.y); v[2] = f2bf(a.z); v[3] = f2bf(a.w);
    v[4] = f2bf(b.x); v[5] = f2bf(b.y); v[6] = f2bf(b.z); v[7] = f2bf(b.w);
    *(short8*)(xb + (size_t)i * 8) = v;
}

// ---------------------------------------------------------------------------
// fold1: Wcat (1024x512 bf16) = [Wfx ; temp[h] * (Ws @ Wx_head)]
//        bias_cat (1024 f32)  = [bfx ; temp[h] * (Ws @ bx_head + bs)]
// ---------------------------------------------------------------------------
__global__ void fold1_kernel(const float* __restrict__ Wx, const float* __restrict__ bx,
                             const float* __restrict__ Wfx, const float* __restrict__ bfx,
                             const float* __restrict__ Ws, const float* __restrict__ bs,
                             const float* __restrict__ temp,
                             short* __restrict__ Wcat, float* __restrict__ bias_cat) {
    int idx = blockIdx.x * 256 + threadIdx.x;   // 0 .. 1024*512-1
    int row = idx >> 9;
    int k = idx & 511;
    float val;
    if (row < 512) {
        val = Wfx[row * 512 + k];
        if (k == 0) bias_cat[row] = bfx[row];
    } else {
        int hg = row - 512;
        int h = hg >> 6, g = hg & 63;
        float t = temp[h];
        float s = 0.f;
        #pragma unroll 8
        for (int d = 0; d < 64; ++d) s += Ws[g * 64 + d] * Wx[(h * 64 + d) * 512 + k];
        val = s * t;
        if (k == 0) {
            float b = 0.f;
            for (int d = 0; d < 64; ++d) b += Ws[g * 64 + d] * bx[h * 64 + d];
            bias_cat[row] = (b + bs[g]) * t;
        }
    }
    Wcat[idx] = f2bf(val);
}

// ---------------------------------------------------------------------------
// gemm_bt: C(M x ncols) = A(M x K) @ B(ncols x K)^T + bias, bf16 MFMA
// R0 structure (m97-style: global_load_lds width=16 staging, XCD-aware 1-D
// grid, 128x128 tile, 4 waves 2x2, 16x16x32 MFMA, 4x4/wave) with BK=64:
// each K-step stages 128x64 per matrix (8 gload_lds) and runs 32 MFMA/wave,
// HALVING the per-step vmcnt(0)+barrier drains (8 instead of 16 for K=512).
// LDS rows are 64 shorts (128 B); chunk swizzle key = row&7 spreads the
// frag ds_read_b128 to the optimal 8 words/bank (measured 0 conflicts at
// this exact layout in prior rounds). Address set, (row,k) mapping, and
// k-accumulation order are IDENTICAL to the BK=32 version (bit-identical C).
// ---------------------------------------------------------------------------
template <bool OUT_F32, bool FUSE_SM>
__global__ __launch_bounds__(256, 4)
void gemm_bt(const short* __restrict__ A, int lda,
             const short* __restrict__ B,           // (ncols x K) bf16 row-major
             const float* __restrict__ bias,
             void* __restrict__ Cp, int ldc,
             int M, int K, int clog2, int Rtiles) {
    __shared__ short As[128 * 64];
    __shared__ short Bs[128 * 64];

    const int id = blockIdx.x;
    const int xcd = id & 7;
    const int s = id >> 3;
    const int cblk = s & ((1 << clog2) - 1);
    const int slice = (Rtiles + 7) >> 3;
    const int rt = xcd * slice + (s >> clog2);
    if (rt >= Rtiles) return;

    const int tid = threadIdx.x;
    const int wid = tid >> 6, lane = tid & 63;
    const int col0 = cblk * 128;
    const int row0 = rt * 128;
    const int wm = (wid >> 1) * 64, wn = (wid & 1) * 64;
    const int lr = lane & 15, lq = lane >> 4;

    // staging map: c = tid + it*256 in [0,1024); row = c>>3, chunk = (c&7)
    // XOR'd with row&7 (pre-swizzled global source, linear LDS dest)
    int st_row[4], st_kc[4];
    #pragma unroll
    for (int it = 0; it < 4; ++it) {
        int c = tid + it * 256;
        st_row[it] = c >> 3;
        st_kc[it] = (c & 7) ^ (st_row[it] & 7);
    }
    // frag-read chunk for kh=0 / kh=1 (row&7 == lr&7 since i*16 ≡ 0 mod 8)
    const int fx0 = (lq ^ (lr & 7)) * 8;
    const int fx1 = ((4 + lq) ^ (lr & 7)) * 8;

    floatx4 acc[4][4];
    #pragma unroll
    for (int i = 0; i < 4; ++i)
        #pragma unroll
        for (int j = 0; j < 4; ++j) acc[i][j] = (floatx4)(0.f);

    const short* Abase = A + (size_t)row0 * lda;
    const short* Bbase = B + (size_t)col0 * lda;

    for (int k0 = 0; k0 < K; k0 += 64) {
        #pragma unroll
        for (int it = 0; it < 4; ++it) {
            short* ldsA = As + (wid * 64 + it * 256) * 8;
            short* ldsB = Bs + (wid * 64 + it * 256) * 8;
            GLOAD_LDS16(Abase + (size_t)st_row[it] * lda + k0 + st_kc[it] * 8, ldsA);
            GLOAD_LDS16(Bbase + (size_t)st_row[it] * lda + k0 + st_kc[it] * 8, ldsB);
        }
        __syncthreads();

        short8 af[4], bfr[4];
        // kh = 0 (k0 .. k0+31)
        #pragma unroll
        for (int i = 0; i < 4; ++i) af[i]  = *(const short8*)&As[(wm + i * 16 + lr) * 64 + fx0];
        #pragma unroll
        for (int j = 0; j < 4; ++j) bfr[j] = *(const short8*)&Bs[(wn + j * 16 + lr) * 64 + fx0];
        #pragma unroll
        for (int i = 0; i < 4; ++i)
            #pragma unroll
            for (int j = 0; j < 4; ++j)
                acc[i][j] = __builtin_amdgcn_mfma_f32_16x16x32_bf16(af[i], bfr[j], acc[i][j], 0, 0, 0);
        // kh = 1 (k0+32 .. k0+63)
        #pragma unroll
        for (int i = 0; i < 4; ++i) af[i]  = *(const short8*)&As[(wm + i * 16 + lr) * 64 + fx1];
        #pragma unroll
        for (int j = 0; j < 4; ++j) bfr[j] = *(const short8*)&Bs[(wn + j * 16 + lr) * 64 + fx1];
        #pragma unroll
        for (int i = 0; i < 4; ++i)
            #pragma unroll
            for (int j = 0; j < 4; ++j)
                acc[i][j] = __builtin_amdgcn_mfma_f32_16x16x32_bf16(af[i], bfr[j], acc[i][j], 0, 0, 0);
        __syncthreads();
    }

    const bool do_sm = FUSE_SM && (col0 >= 512);
    float bcol[4];
    #pragma unroll
    for (int j = 0; j < 4; ++j) bcol[j] = bias[col0 + wn + j * 16 + lr];

    #pragma unroll
    for (int i = 0; i < 4; ++i) {
        #pragma unroll
        for (int r = 0; r < 4; ++r) {
            int grow = row0 + wm + i * 16 + lq * 4 + r;
            float v[4];
            #pragma unroll
            for (int j = 0; j < 4; ++j) v[j] = acc[i][j][r] + bcol[j];
            if (do_sm) {
                float m = fmaxf(fmaxf(v[0], v[1]), fmaxf(v[2], v[3]));
                #pragma unroll
                for (int off = 1; off < 16; off <<= 1) m = fmaxf(m, __shfl_xor(m, off));
                float sum = 0.f;
                #pragma unroll
                for (int j = 0; j < 4; ++j) { v[j] = __expf(v[j] - m); sum += v[j]; }
                #pragma unroll
                for (int off = 1; off < 16; off <<= 1) sum += __shfl_xor(sum, off);
                float inv = 1.f / sum;
                #pragma unroll
                for (int j = 0; j < 4; ++j) v[j] *= inv;
            }
            if (grow < M) {
                #pragma unroll
                for (int j = 0; j < 4; ++j) {
                    int gcol = col0 + wn + j * 16 + lr;
                    if constexpr (OUT_F32) ((float*)Cp)[(size_t)grow * ldc + gcol] = v[j];
                    else                   ((short*)Cp)[(size_t)grow * ldc + gcol] = f2bf(v[j]);
                }
            }
        }
    }
}

// ---------------------------------------------------------------------------
// pool_mfma: tok_raw[h,g,d] += sum_n w[n,h,g]*fx[n,h,d]; norm[h,g] += sum_n w
// MFMA formulation ("TN" gemm): stage 32n x 64c tiles row-major, fill frags
// with per-lane ds_read_u16 (transposed read). LDS stride 72 shorts (16B
// aligned for b128 staging) + 16-col rotation per 8-row group -> frag reads
// land 2 lanes/bank (free). Waves tile 2x2 over (g,d); norm via a constant
// all-ones B-frag MFMA. Split-K over grid.x, f32 atomicAdd epilogue.
// chunk must be a multiple of 32; N % 32 == 0.
// ---------------------------------------------------------------------------
__global__ __launch_bounds__(256)
void pool_mfma(const short* __restrict__ mid, float* __restrict__ tok_raw,
               float* __restrict__ norm, int N, int chunk) {
    const int h = blockIdx.y;
    const int n0 = blockIdx.x * chunk;
    if (n0 >= N) return;
    const int ksteps = (min(chunk, N - n0)) >> 5;

    const int tid = threadIdx.x;
    const int wid = tid >> 6, lane = tid & 63;
    const int lr = lane & 15, lq = lane >> 4;
    const int wg = (wid >> 1) * 32, wd = (wid & 1) * 32;

    __shared__ short wt[32 * 72];
    __shared__ short ft[32 * 72];

    // staging: thread -> row n = tid>>3 (0..31), col chunk c0 = (tid&7)*8
    const int sn = tid >> 3;
    const int sc0 = (tid & 7) * 8;
    const int scr = (sc0 + 16 * ((sn >> 3) & 3)) & 63;   // rotated col
    const int st_off = sn * 72 + scr;

    // frag reads: row k = lq*8+j, col (c + 16*lq) & 63
    const int ra = ((wg + lr) + 16 * lq) & 63;           // A cols (i adds 16)
    const int rb = ((wd + lr) + 16 * lq) & 63;           // B cols (j adds 16)

    const short* wbase = mid + (size_t)n0 * 1024 + 512 + h * 64;
    const short* fbase = mid + (size_t)n0 * 1024 + h * 64;

    floatx4 acc[2][2];
    #pragma unroll
    for (int i = 0; i < 2; ++i)
        #pragma unroll
        for (int j = 0; j < 2; ++j) acc[i][j] = (floatx4)(0.f);
    floatx4 accn[2];
    accn[0] = (floatx4)(0.f); accn[1] = (floatx4)(0.f);

    short8 ones;
    #pragma unroll
    for (int j = 0; j < 8; ++j) ones[j] = (short)0x3F80;   // bf16 1.0

    for (int ks = 0; ks < ksteps; ++ks) {
        const size_t roff = (size_t)(ks * 32 + sn) * 1024;
        short8 wv = *(const short8*)(wbase + roff + sc0);
        short8 fv = *(const short8*)(fbase + roff + sc0);
        __syncthreads();                 // previous iter's frag reads done
        *(short8*)&wt[st_off] = wv;
        *(short8*)&ft[st_off] = fv;
        __syncthreads();

        short8 af[2], bf_[2];
        #pragma unroll
        for (int i = 0; i < 2; ++i) {
            short tmpv[8];
            #pragma unroll
            for (int j = 0; j < 8; ++j)
                tmpv[j] = wt[(lq * 8 + j) * 72 + ((ra + i * 16) & 63)];
            af[i] = *(const short8*)tmpv;
        }
        #pragma unroll
        for (int j2 = 0; j2 < 2; ++j2) {
            short tmpv[8];
            #pragma unroll
            for (int j = 0; j < 8; ++j)
                tmpv[j] = ft[(lq * 8 + j) * 72 + ((rb + j2 * 16) & 63)];
            bf_[j2] = *(const short8*)tmpv;
        }
        #pragma unroll
        for (int i = 0; i < 2; ++i)
            #pragma unroll
            for (int j = 0; j < 2; ++j)
                acc[i][j] = __builtin_amdgcn_mfma_f32_16x16x32_bf16(af[i], bf_[j], acc[i][j], 0, 0, 0);
        if (wd == 0) {
            #pragma unroll
            for (int i = 0; i < 2; ++i)
                accn[i] = __builtin_amdgcn_mfma_f32_16x16x32_bf16(af[i], ones, accn[i], 0, 0, 0);
        }
    }

    // epilogue: D col = lane&15, row = lq*4 + r
    #pragma unroll
    for (int i = 0; i < 2; ++i) {
        #pragma unroll
        for (int r = 0; r < 4; ++r) {
            int g = wg + i * 16 + lq * 4 + r;
            #pragma unroll
            for (int j = 0; j < 2; ++j) {
                int d = wd + j * 16 + lr;
                atomicAdd(&tok_raw[(h * 64 + g) * 64 + d], acc[i][j][r]);
            }
        }
    }
    if (wd == 0 && lr == 0) {
        #pragma unroll
        for (int i = 0; i < 2; ++i)
            #pragma unroll
            for (int r = 0; r < 4; ++r)
                atomicAdd(&norm[h * 64 + wg + i * 16 + lq * 4 + r], accn[i][r]);
    }
}

// ---------------------------------------------------------------------------
// attn: per head, G=64 tokens. 256 threads (4 waves): thread (g=tid&63,
// part=tid>>6) computes 16/64 outputs per matmul stage. All f32.
// ---------------------------------------------------------------------------
__global__ __launch_bounds__(256)
void attn_kernel(const float* __restrict__ tok_raw, const float* __restrict__ norm,
                 const float* __restrict__ Wq, const float* __restrict__ Wk,
                 const float* __restrict__ Wv, const float* __restrict__ Wo,
                 float* __restrict__ out_tok) {
    const int h = blockIdx.x;
    const int tid = threadIdx.x;
    const int g = tid & 63, part = tid >> 6;
    const int o0 = part * 16;

    __shared__ float tk[64][65];
    __shared__ float qq[64][65];
    __shared__ float kk[64][65];
    __shared__ float vv[64][65];
    __shared__ float pp[64][65];
    __shared__ float od[64][65];

    const float inv = 1.f / (norm[h * 64 + g] + EPSF);
    #pragma unroll
    for (int dd = 0; dd < 16; ++dd) {
        int d = o0 + dd;
        tk[g][d] = tok_raw[(size_t)(h * 64 + g) * 64 + d] * inv;
    }
    __syncthreads();

    float t[64];
    #pragma unroll
    for (int d = 0; d < 64; ++d) t[d] = tk[g][d];
    #pragma unroll
    for (int oo = 0; oo < 16; ++oo) {
        int o = o0 + oo;
        float sq = 0.f, sk = 0.f, sv = 0.f;
        #pragma unroll
        for (int d = 0; d < 64; ++d) {
            float td = t[d];
            sq += td * Wq[o * 64 + d];
            sk += td * Wk[o * 64 + d];
            sv += td * Wv[o * 64 + d];
        }
        qq[g][o] = sq; kk[g][o] = sk; vv[g][o] = sv;
    }
    __syncthreads();

    float q[64];
    #pragma unroll
    for (int o = 0; o < 64; ++o) q[o] = qq[g][o];
    #pragma unroll
    for (int jj = 0; jj < 16; ++jj) {
        int j = o0 + jj;
        float s = 0.f;
        #pragma unroll
        for (int o = 0; o < 64; ++o) s += q[o] * kk[j][o];
        pp[g][j] = s * 0.125f;
    }
    __syncthreads();

    float sr[64];
    float mx = -1e30f;
    #pragma unroll
    for (int j = 0; j < 64; ++j) { sr[j] = pp[g][j]; mx = fmaxf(mx, sr[j]); }
    float sum = 0.f;
    #pragma unroll
    for (int j = 0; j < 64; ++j) { sr[j] = __expf(sr[j] - mx); sum += sr[j]; }
    const float isum = 1.f / sum;

    #pragma unroll
    for (int dd = 0; dd < 16; ++dd) {
        int d = o0 + dd;
        float a = 0.f;
        #pragma unroll
        for (int j = 0; j < 64; ++j) a += sr[j] * vv[j][d];
        od[g][d] = a * isum;
    }
    __syncthreads();

    float ot[64];
    #pragma unroll
    for (int d = 0; d < 64; ++d) ot[d] = od[g][d];
    #pragma unroll
    for (int oo = 0; oo < 16; ++oo) {
        int o = o0 + oo;
        float a = 0.f;
        #pragma unroll
        for (int d = 0; d < 64; ++d) a += ot[d] * Wo[o * 64 + d];
        out_tok[(size_t)(h * 64 + g) * 64 + o] = a;
    }
}

// ---------------------------------------------------------------------------
// fold2: V[o, h*64+g] = sum_d out_tok[h,g,d] * Wout[o, h*64+d]  (bf16 out)
// ---------------------------------------------------------------------------
__global__ void fold2_kernel(const float* __restrict__ out_tok,
                             const float* __restrict__ Wout, short* __restrict__ Vbf) {
    int idx = blockIdx.x * 256 + threadIdx.x;
    int o = idx >> 9, hg = idx & 511;
    int h = hg >> 6;
    const float* ot = out_tok + (size_t)hg * 64;
    const float* wo = Wout + (size_t)o * 512 + h * 64;
    float s = 0.f;
    #pragma unroll 8
    for (int d = 0; d < 64; ++d) s += ot[d] * wo[d];
    Vbf[idx] = f2bf(s);
}

// ---------------------------------------------------------------------------
extern "C" void kernel_launch(void* const* d_in, const int* in_sizes, int n_in,
                              void* d_out, int out_size, void* d_ws, size_t ws_size,
                              hipStream_t stream) {
    const float* x    = (const float*)d_in[0];
    const float* Wx   = (const float*)d_in[1];
    const float* bx   = (const float*)d_in[2];
    const float* Wfx  = (const float*)d_in[3];
    const float* bfx  = (const float*)d_in[4];
    const float* Ws   = (const float*)d_in[5];
    const float* bs   = (const float*)d_in[6];
    const float* temp = (const float*)d_in[7];
    const float* Wq   = (const float*)d_in[8];
    const float* Wk   = (const float*)d_in[9];
    const float* Wv   = (const float*)d_in[10];
    const float* Wo   = (const float*)d_in[11];
    const float* Wout = (const float*)d_in[12];
    const float* bout = (const float*)d_in[13];

    const int N = in_sizes[0] / HID;

    char* p = (char*)d_ws;
    short* mid = (short*)p;           p += (size_t)N * 1024 * 2;       // fx | w (bf16)
    short* Wcat = (short*)p;          p += (size_t)1024 * 512 * 2;
    float* bias_cat = (float*)p;      p += 1024 * 4;
    float* tok_raw = (float*)p;       p += (size_t)NH * GG * DD * 4;   // contiguous with norm
    float* norm_ = (float*)p;         p += (size_t)NH * GG * 4;
    float* out_tok = (float*)p;       p += (size_t)NH * GG * DD * 4;
    short* Vbf = (short*)p;           p += (size_t)512 * 512 * 2;
    short* x_bf = (short*)d_out;     // d_out (N*512 f32) hosts x_bf until GEMM2

    cast_kernel<<<(N * 512 / 8 + 255) / 256, 256, 0, stream>>>(x, x_bf, N * 512 / 8);
    fold1_kernel<<<2048, 256, 0, stream>>>(Wx, bx, Wfx, bfx, Ws, bs, temp, Wcat, bias_cat);

    const int R = (N + 127) / 128;
    const int slice = (R + 7) / 8;

    // GEMM1: C=8 col tiles, fused softmax on logits half
    gemm_bt<false, true><<<8 * slice * 8, 256, 0, stream>>>(
        x_bf, HID, Wcat, bias_cat, (void*)mid, 1024, N, 512, 3, R);

    hipMemsetAsync(tok_raw, 0, (size_t)(NH * GG * DD + NH * GG) * 4, stream);

    // pool: split-K MFMA; chunk multiple of 32 (N=100000 is a multiple of 32)
    const int chunk = 544;                       // 17 k-steps per block
    dim3 g2((N + chunk - 1) / chunk, 8);
    pool_mfma<<<g2, 256, 0, stream>>>(mid, tok_raw, norm_, N, chunk);

    attn_kernel<<<8, 256, 0, stream>>>(tok_raw, norm_, Wq, Wk, Wv, Wo, out_tok);

    fold2_kernel<<<1024, 256, 0, stream>>>(out_tok, Wout, Vbf);

    // GEMM2: C=4 col tiles (A = w half of mid, bf16; output f32 + bout)
    gemm_bt<true, false><<<8 * slice * 4, 256, 0, stream>>>(
        mid + 512, 1024, Vbf, bout, d_out, HID, N, 512, 2, R);
}

// Round 6
// 738.550 us; speedup vs baseline: 1.2001x; 1.1475x over previous
//
#include <hip/hip_runtime.h>
#include <hip/hip_bf16.h>

#define HID 512
#define NH  8
#define DD  64
#define GG  64
#define EPSF 1e-5f

typedef __attribute__((ext_vector_type(8))) short short8;
typedef __attribute__((ext_vector_type(4))) float floatx4;

__device__ __forceinline__ short f2bf(float f) {
    union { float f; unsigned u; } v; v.f = f;
    unsigned r = v.u + 0x7fffu + ((v.u >> 16) & 1u);
    return (short)(r >> 16);
}

#define GLOAD_LDS16(g, l) __builtin_amdgcn_global_load_lds( \
    (const __attribute__((address_space(1))) unsigned int*)(g), \
    (__attribute__((address_space(3))) unsigned int*)(l), 16, 0, 0)

// ---------------------------------------------------------------------------
// fold1: Wcat (1024x512 bf16) = [Wfx ; temp[h] * (Ws @ Wx_head)]
//        bias_cat (1024 f32)  = [bfx ; temp[h] * (Ws @ bx_head + bs)]
// ---------------------------------------------------------------------------
__global__ void fold1_kernel(const float* __restrict__ Wx, const float* __restrict__ bx,
                             const float* __restrict__ Wfx, const float* __restrict__ bfx,
                             const float* __restrict__ Ws, const float* __restrict__ bs,
                             const float* __restrict__ temp,
                             short* __restrict__ Wcat, float* __restrict__ bias_cat) {
    int idx = blockIdx.x * 256 + threadIdx.x;   // 0 .. 1024*512-1
    int row = idx >> 9;
    int k = idx & 511;
    float val;
    if (row < 512) {
        val = Wfx[row * 512 + k];
        if (k == 0) bias_cat[row] = bfx[row];
    } else {
        int hg = row - 512;
        int h = hg >> 6, g = hg & 63;
        float t = temp[h];
        float s = 0.f;
        #pragma unroll 8
        for (int d = 0; d < 64; ++d) s += Ws[g * 64 + d] * Wx[(h * 64 + d) * 512 + k];
        val = s * t;
        if (k == 0) {
            float b = 0.f;
            for (int d = 0; d < 64; ++d) b += Ws[g * 64 + d] * bx[h * 64 + d];
            bias_cat[row] = (b + bs[g]) * t;
        }
    }
    Wcat[idx] = f2bf(val);
}

// ---------------------------------------------------------------------------
// gemm1_fused: mid(M x 1024 bf16) = softmax-fused [x @ Wcat^T + bias], where
// A is read DIRECTLY from f32 x (cast kernel fused away):
//  - A staging: one-deep pipelined reg path. Prefetch next K-step's 8xfloat4
//    right after the barrier (latency hides under frag-reads+MFMA), convert
//    with scalar f2bf (bit-identical to the old cast kernel; compiler
//    schedules the int-ops freely -- no inline asm, per m240), ds_write_b128
//    the SAME swizzled LDS image the gload_lds path produced.
//  - B staging: global_load_lds width=16 unchanged (Wcat is L2-hot).
//  - Phantom rows >= M clamp their A-reads to row M-1 (x has no tail slack);
//    their stores stay masked by grow < M.
// 128x128 tile, BK=64, 4 waves 2x2, 16x16x32 MFMA, XCD-aware 1-D grid.
// ---------------------------------------------------------------------------
__global__ __launch_bounds__(256, 4)
void gemm1_fused(const float* __restrict__ X,          // (M x 512) f32
                 const short* __restrict__ B,          // (1024 x 512) bf16
                 const float* __restrict__ bias,
                 short* __restrict__ Cp,               // (M x 1024) bf16
                 int M, int clog2, int Rtiles) {
    const int K = 512, lda = 512, ldc = 1024;
    __shared__ short As[128 * 64];
    __shared__ short Bs[128 * 64];

    const int id = blockIdx.x;
    const int xcd = id & 7;
    const int s = id >> 3;
    const int cblk = s & ((1 << clog2) - 1);
    const int slice = (Rtiles + 7) >> 3;
    const int rt = xcd * slice + (s >> clog2);
    if (rt >= Rtiles) return;

    const int tid = threadIdx.x;
    const int wid = tid >> 6, lane = tid & 63;
    const int col0 = cblk * 128;
    const int row0 = rt * 128;
    const int wm = (wid >> 1) * 64, wn = (wid & 1) * 64;
    const int lr = lane & 15, lq = lane >> 4;

    // staging map: c = tid + it*256 in [0,1024); row = c>>3, chunk (c&7)
    // XOR'd with row&7 (swizzled source chunk, linear LDS dest)
    int st_row[4], st_kc[4];
    const float* aptr[4];
    #pragma unroll
    for (int it = 0; it < 4; ++it) {
        int c = tid + it * 256;
        st_row[it] = c >> 3;
        st_kc[it] = (c & 7) ^ (st_row[it] & 7);
        int ar = min(row0 + st_row[it], M - 1);       // clamp phantom rows
        aptr[it] = X + (size_t)ar * lda + st_kc[it] * 8;
    }
    // frag-read chunk for kh=0 / kh=1 (row&7 == lr&7 since i*16 ≡ 0 mod 8)
    const int fx0 = (lq ^ (lr & 7)) * 8;
    const int fx1 = ((4 + lq) ^ (lr & 7)) * 8;

    floatx4 acc[4][4];
    #pragma unroll
    for (int i = 0; i < 4; ++i)
        #pragma unroll
        for (int j = 0; j < 4; ++j) acc[i][j] = (floatx4)(0.f);

    const short* Bbase = B + (size_t)col0 * lda;

    // prologue: prefetch A regs for k0 = 0
    float4 fa[4][2];
    #pragma unroll
    for (int it = 0; it < 4; ++it) {
        fa[it][0] = *(const float4*)(aptr[it]);
        fa[it][1] = *(const float4*)(aptr[it] + 4);
    }

    for (int k0 = 0; k0 < K; k0 += 64) {
        // B: async gload_lds for this step (latency overlaps the cvt VALU)
        #pragma unroll
        for (int it = 0; it < 4; ++it) {
            short* ldsB = Bs + (wid * 64 + it * 256) * 8;
            GLOAD_LDS16(Bbase + (size_t)st_row[it] * lda + k0 + st_kc[it] * 8, ldsB);
        }
        // A: convert current regs, write swizzled LDS image (b128 store)
        #pragma unroll
        for (int it = 0; it < 4; ++it) {
            short8 sv;
            sv[0] = f2bf(fa[it][0].x); sv[1] = f2bf(fa[it][0].y);
            sv[2] = f2bf(fa[it][0].z); sv[3] = f2bf(fa[it][0].w);
            sv[4] = f2bf(fa[it][1].x); sv[5] = f2bf(fa[it][1].y);
            sv[6] = f2bf(fa[it][1].z); sv[7] = f2bf(fa[it][1].w);
            *(short8*)&As[(size_t)(tid + it * 256) * 8] = sv;
        }
        __syncthreads();   // drains B vmcnt + A lds writes

        // prefetch next K-step's A regs (independent; hides under MFMA)
        const int kn = (k0 + 64 < K) ? (k0 + 64) : 0;
        #pragma unroll
        for (int it = 0; it < 4; ++it) {
            fa[it][0] = *(const float4*)(aptr[it] + kn);
            fa[it][1] = *(const float4*)(aptr[it] + kn + 4);
        }

        short8 af[4], bfr[4];
        // kh = 0 (k0 .. k0+31)
        #pragma unroll
        for (int i = 0; i < 4; ++i) af[i]  = *(const short8*)&As[(wm + i * 16 + lr) * 64 + fx0];
        #pragma unroll
        for (int j = 0; j < 4; ++j) bfr[j] = *(const short8*)&Bs[(wn + j * 16 + lr) * 64 + fx0];
        #pragma unroll
        for (int i = 0; i < 4; ++i)
            #pragma unroll
            for (int j = 0; j < 4; ++j)
                acc[i][j] = __builtin_amdgcn_mfma_f32_16x16x32_bf16(af[i], bfr[j], acc[i][j], 0, 0, 0);
        // kh = 1 (k0+32 .. k0+63)
        #pragma unroll
        for (int i = 0; i < 4; ++i) af[i]  = *(const short8*)&As[(wm + i * 16 + lr) * 64 + fx1];
        #pragma unroll
        for (int j = 0; j < 4; ++j) bfr[j] = *(const short8*)&Bs[(wn + j * 16 + lr) * 64 + fx1];
        #pragma unroll
        for (int i = 0; i < 4; ++i)
            #pragma unroll
            for (int j = 0; j < 4; ++j)
                acc[i][j] = __builtin_amdgcn_mfma_f32_16x16x32_bf16(af[i], bfr[j], acc[i][j], 0, 0, 0);
        __syncthreads();
    }

    const bool do_sm = (col0 >= 512);
    float bcol[4];
    #pragma unroll
    for (int j = 0; j < 4; ++j) bcol[j] = bias[col0 + wn + j * 16 + lr];

    #pragma unroll
    for (int i = 0; i < 4; ++i) {
        #pragma unroll
        for (int r = 0; r < 4; ++r) {
            int grow = row0 + wm + i * 16 + lq * 4 + r;
            float v[4];
            #pragma unroll
            for (int j = 0; j < 4; ++j) v[j] = acc[i][j][r] + bcol[j];
            if (do_sm) {
                float m = fmaxf(fmaxf(v[0], v[1]), fmaxf(v[2], v[3]));
                #pragma unroll
                for (int off = 1; off < 16; off <<= 1) m = fmaxf(m, __shfl_xor(m, off));
                float sum = 0.f;
                #pragma unroll
                for (int j = 0; j < 4; ++j) { v[j] = __expf(v[j] - m); sum += v[j]; }
                #pragma unroll
                for (int off = 1; off < 16; off <<= 1) sum += __shfl_xor(sum, off);
                float inv = 1.f / sum;
                #pragma unroll
                for (int j = 0; j < 4; ++j) v[j] *= inv;
            }
            if (grow < M) {
                #pragma unroll
                for (int j = 0; j < 4; ++j) {
                    int gcol = col0 + wn + j * 16 + lr;
                    Cp[(size_t)grow * ldc + gcol] = f2bf(v[j]);
                }
            }
        }
    }
}

// ---------------------------------------------------------------------------
// gemm_bt: C(M x ncols) = A(M x K) @ B(ncols x K)^T + bias, bf16 MFMA
// (R4 structure: gload_lds width=16 both operands, BK=64, 128x128 tile,
//  4 waves 2x2, 16x16x32 MFMA, XCD-aware 1-D grid.) Used for GEMM2.
// ---------------------------------------------------------------------------
template <bool OUT_F32, bool FUSE_SM>
__global__ __launch_bounds__(256, 4)
void gemm_bt(const short* __restrict__ A, int lda,
             const short* __restrict__ B,           // (ncols x K) bf16 row-major
             const float* __restrict__ bias,
             void* __restrict__ Cp, int ldc,
             int M, int K, int clog2, int Rtiles) {
    __shared__ short As[128 * 64];
    __shared__ short Bs[128 * 64];

    const int id = blockIdx.x;
    const int xcd = id & 7;
    const int s = id >> 3;
    const int cblk = s & ((1 << clog2) - 1);
    const int slice = (Rtiles + 7) >> 3;
    const int rt = xcd * slice + (s >> clog2);
    if (rt >= Rtiles) return;

    const int tid = threadIdx.x;
    const int wid = tid >> 6, lane = tid & 63;
    const int col0 = cblk * 128;
    const int row0 = rt * 128;
    const int wm = (wid >> 1) * 64, wn = (wid & 1) * 64;
    const int lr = lane & 15, lq = lane >> 4;

    int st_row[4], st_kc[4];
    #pragma unroll
    for (int it = 0; it < 4; ++it) {
        int c = tid + it * 256;
        st_row[it] = c >> 3;
        st_kc[it] = (c & 7) ^ (st_row[it] & 7);
    }
    const int fx0 = (lq ^ (lr & 7)) * 8;
    const int fx1 = ((4 + lq) ^ (lr & 7)) * 8;

    floatx4 acc[4][4];
    #pragma unroll
    for (int i = 0; i < 4; ++i)
        #pragma unroll
        for (int j = 0; j < 4; ++j) acc[i][j] = (floatx4)(0.f);

    const short* Abase = A + (size_t)row0 * lda;
    const short* Bbase = B + (size_t)col0 * lda;

    for (int k0 = 0; k0 < K; k0 += 64) {
        #pragma unroll
        for (int it = 0; it < 4; ++it) {
            short* ldsA = As + (wid * 64 + it * 256) * 8;
            short* ldsB = Bs + (wid * 64 + it * 256) * 8;
            GLOAD_LDS16(Abase + (size_t)st_row[it] * lda + k0 + st_kc[it] * 8, ldsA);
            GLOAD_LDS16(Bbase + (size_t)st_row[it] * lda + k0 + st_kc[it] * 8, ldsB);
        }
        __syncthreads();

        short8 af[4], bfr[4];
        #pragma unroll
        for (int i = 0; i < 4; ++i) af[i]  = *(const short8*)&As[(wm + i * 16 + lr) * 64 + fx0];
        #pragma unroll
        for (int j = 0; j < 4; ++j) bfr[j] = *(const short8*)&Bs[(wn + j * 16 + lr) * 64 + fx0];
        #pragma unroll
        for (int i = 0; i < 4; ++i)
            #pragma unroll
            for (int j = 0; j < 4; ++j)
                acc[i][j] = __builtin_amdgcn_mfma_f32_16x16x32_bf16(af[i], bfr[j], acc[i][j], 0, 0, 0);
        #pragma unroll
        for (int i = 0; i < 4; ++i) af[i]  = *(const short8*)&As[(wm + i * 16 + lr) * 64 + fx1];
        #pragma unroll
        for (int j = 0; j < 4; ++j) bfr[j] = *(const short8*)&Bs[(wn + j * 16 + lr) * 64 + fx1];
        #pragma unroll
        for (int i = 0; i < 4; ++i)
            #pragma unroll
            for (int j = 0; j < 4; ++j)
                acc[i][j] = __builtin_amdgcn_mfma_f32_16x16x32_bf16(af[i], bfr[j], acc[i][j], 0, 0, 0);
        __syncthreads();
    }

    const bool do_sm = FUSE_SM && (col0 >= 512);
    float bcol[4];
    #pragma unroll
    for (int j = 0; j < 4; ++j) bcol[j] = bias[col0 + wn + j * 16 + lr];

    #pragma unroll
    for (int i = 0; i < 4; ++i) {
        #pragma unroll
        for (int r = 0; r < 4; ++r) {
            int grow = row0 + wm + i * 16 + lq * 4 + r;
            float v[4];
            #pragma unroll
            for (int j = 0; j < 4; ++j) v[j] = acc[i][j][r] + bcol[j];
            if (do_sm) {
                float m = fmaxf(fmaxf(v[0], v[1]), fmaxf(v[2], v[3]));
                #pragma unroll
                for (int off = 1; off < 16; off <<= 1) m = fmaxf(m, __shfl_xor(m, off));
                float sum = 0.f;
                #pragma unroll
                for (int j = 0; j < 4; ++j) { v[j] = __expf(v[j] - m); sum += v[j]; }
                #pragma unroll
                for (int off = 1; off < 16; off <<= 1) sum += __shfl_xor(sum, off);
                float inv = 1.f / sum;
                #pragma unroll
                for (int j = 0; j < 4; ++j) v[j] *= inv;
            }
            if (grow < M) {
                #pragma unroll
                for (int j = 0; j < 4; ++j) {
                    int gcol = col0 + wn + j * 16 + lr;
                    if constexpr (OUT_F32) ((float*)Cp)[(size_t)grow * ldc + gcol] = v[j];
                    else                   ((short*)Cp)[(size_t)grow * ldc + gcol] = f2bf(v[j]);
                }
            }
        }
    }
}

// ---------------------------------------------------------------------------
// pool_mfma: tok_raw[h,g,d] += sum_n w[n,h,g]*fx[n,h,d]; norm[h,g] += sum_n w
// (unchanged)
// ---------------------------------------------------------------------------
__global__ __launch_bounds__(256)
void pool_mfma(const short* __restrict__ mid, float* __restrict__ tok_raw,
               float* __restrict__ norm, int N, int chunk) {
    const int h = blockIdx.y;
    const int n0 = blockIdx.x * chunk;
    if (n0 >= N) return;
    const int ksteps = (min(chunk, N - n0)) >> 5;

    const int tid = threadIdx.x;
    const int wid = tid >> 6, lane = tid & 63;
    const int lr = lane & 15, lq = lane >> 4;
    const int wg = (wid >> 1) * 32, wd = (wid & 1) * 32;

    __shared__ short wt[32 * 72];
    __shared__ short ft[32 * 72];

    const int sn = tid >> 3;
    const int sc0 = (tid & 7) * 8;
    const int scr = (sc0 + 16 * ((sn >> 3) & 3)) & 63;   // rotated col
    const int st_off = sn * 72 + scr;

    const int ra = ((wg + lr) + 16 * lq) & 63;           // A cols (i adds 16)
    const int rb = ((wd + lr) + 16 * lq) & 63;           // B cols (j adds 16)

    const short* wbase = mid + (size_t)n0 * 1024 + 512 + h * 64;
    const short* fbase = mid + (size_t)n0 * 1024 + h * 64;

    floatx4 acc[2][2];
    #pragma unroll
    for (int i = 0; i < 2; ++i)
        #pragma unroll
        for (int j = 0; j < 2; ++j) acc[i][j] = (floatx4)(0.f);
    floatx4 accn[2];
    accn[0] = (floatx4)(0.f); accn[1] = (floatx4)(0.f);

    short8 ones;
    #pragma unroll
    for (int j = 0; j < 8; ++j) ones[j] = (short)0x3F80;   // bf16 1.0

    for (int ks = 0; ks < ksteps; ++ks) {
        const size_t roff = (size_t)(ks * 32 + sn) * 1024;
        short8 wv = *(const short8*)(wbase + roff + sc0);
        short8 fv = *(const short8*)(fbase + roff + sc0);
        __syncthreads();                 // previous iter's frag reads done
        *(short8*)&wt[st_off] = wv;
        *(short8*)&ft[st_off] = fv;
        __syncthreads();

        short8 af[2], bf_[2];
        #pragma unroll
        for (int i = 0; i < 2; ++i) {
            short tmpv[8];
            #pragma unroll
            for (int j = 0; j < 8; ++j)
                tmpv[j] = wt[(lq * 8 + j) * 72 + ((ra + i * 16) & 63)];
            af[i] = *(const short8*)tmpv;
        }
        #pragma unroll
        for (int j2 = 0; j2 < 2; ++j2) {
            short tmpv[8];
            #pragma unroll
            for (int j = 0; j < 8; ++j)
                tmpv[j] = ft[(lq * 8 + j) * 72 + ((rb + j2 * 16) & 63)];
            bf_[j2] = *(const short8*)tmpv;
        }
        #pragma unroll
        for (int i = 0; i < 2; ++i)
            #pragma unroll
            for (int j = 0; j < 2; ++j)
                acc[i][j] = __builtin_amdgcn_mfma_f32_16x16x32_bf16(af[i], bf_[j], acc[i][j], 0, 0, 0);
        if (wd == 0) {
            #pragma unroll
            for (int i = 0; i < 2; ++i)
                accn[i] = __builtin_amdgcn_mfma_f32_16x16x32_bf16(af[i], ones, accn[i], 0, 0, 0);
        }
    }

    #pragma unroll
    for (int i = 0; i < 2; ++i) {
        #pragma unroll
        for (int r = 0; r < 4; ++r) {
            int g = wg + i * 16 + lq * 4 + r;
            #pragma unroll
            for (int j = 0; j < 2; ++j) {
                int d = wd + j * 16 + lr;
                atomicAdd(&tok_raw[(h * 64 + g) * 64 + d], acc[i][j][r]);
            }
        }
    }
    if (wd == 0 && lr == 0) {
        #pragma unroll
        for (int i = 0; i < 2; ++i)
            #pragma unroll
            for (int r = 0; r < 4; ++r)
                atomicAdd(&norm[h * 64 + wg + i * 16 + lq * 4 + r], accn[i][r]);
    }
}

// ---------------------------------------------------------------------------
// attn: per head, G=64 tokens (unchanged)
// ---------------------------------------------------------------------------
__global__ __launch_bounds__(256)
void attn_kernel(const float* __restrict__ tok_raw, const float* __restrict__ norm,
                 const float* __restrict__ Wq, const float* __restrict__ Wk,
                 const float* __restrict__ Wv, const float* __restrict__ Wo,
                 float* __restrict__ out_tok) {
    const int h = blockIdx.x;
    const int tid = threadIdx.x;
    const int g = tid & 63, part = tid >> 6;
    const int o0 = part * 16;

    __shared__ float tk[64][65];
    __shared__ float qq[64][65];
    __shared__ float kk[64][65];
    __shared__ float vv[64][65];
    __shared__ float pp[64][65];
    __shared__ float od[64][65];

    const float inv = 1.f / (norm[h * 64 + g] + EPSF);
    #pragma unroll
    for (int dd = 0; dd < 16; ++dd) {
        int d = o0 + dd;
        tk[g][d] = tok_raw[(size_t)(h * 64 + g) * 64 + d] * inv;
    }
    __syncthreads();

    float t[64];
    #pragma unroll
    for (int d = 0; d < 64; ++d) t[d] = tk[g][d];
    #pragma unroll
    for (int oo = 0; oo < 16; ++oo) {
        int o = o0 + oo;
        float sq = 0.f, sk = 0.f, sv = 0.f;
        #pragma unroll
        for (int d = 0; d < 64; ++d) {
            float td = t[d];
            sq += td * Wq[o * 64 + d];
            sk += td * Wk[o * 64 + d];
            sv += td * Wv[o * 64 + d];
        }
        qq[g][o] = sq; kk[g][o] = sk; vv[g][o] = sv;
    }
    __syncthreads();

    float q[64];
    #pragma unroll
    for (int o = 0; o < 64; ++o) q[o] = qq[g][o];
    #pragma unroll
    for (int jj = 0; jj < 16; ++jj) {
        int j = o0 + jj;
        float s = 0.f;
        #pragma unroll
        for (int o = 0; o < 64; ++o) s += q[o] * kk[j][o];
        pp[g][j] = s * 0.125f;
    }
    __syncthreads();

    float sr[64];
    float mx = -1e30f;
    #pragma unroll
    for (int j = 0; j < 64; ++j) { sr[j] = pp[g][j]; mx = fmaxf(mx, sr[j]); }
    float sum = 0.f;
    #pragma unroll
    for (int j = 0; j < 64; ++j) { sr[j] = __expf(sr[j] - mx); sum += sr[j]; }
    const float isum = 1.f / sum;

    #pragma unroll
    for (int dd = 0; dd < 16; ++dd) {
        int d = o0 + dd;
        float a = 0.f;
        #pragma unroll
        for (int j = 0; j < 64; ++j) a += sr[j] * vv[j][d];
        od[g][d] = a * isum;
    }
    __syncthreads();

    float ot[64];
    #pragma unroll
    for (int d = 0; d < 64; ++d) ot[d] = od[g][d];
    #pragma unroll
    for (int oo = 0; oo < 16; ++oo) {
        int o = o0 + oo;
        float a = 0.f;
        #pragma unroll
        for (int d = 0; d < 64; ++d) a += ot[d] * Wo[o * 64 + d];
        out_tok[(size_t)(h * 64 + g) * 64 + o] = a;
    }
}

// ---------------------------------------------------------------------------
// fold2: V[o, h*64+g] = sum_d out_tok[h,g,d] * Wout[o, h*64+d]  (bf16 out)
// ---------------------------------------------------------------------------
__global__ void fold2_kernel(const float* __restrict__ out_tok,
                             const float* __restrict__ Wout, short* __restrict__ Vbf) {
    int idx = blockIdx.x * 256 + threadIdx.x;
    int o = idx >> 9, hg = idx & 511;
    int h = hg >> 6;
    const float* ot = out_tok + (size_t)hg * 64;
    const float* wo = Wout + (size_t)o * 512 + h * 64;
    float s = 0.f;
    #pragma unroll 8
    for (int d = 0; d < 64; ++d) s += ot[d] * wo[d];
    Vbf[idx] = f2bf(s);
}

// ---------------------------------------------------------------------------
extern "C" void kernel_launch(void* const* d_in, const int* in_sizes, int n_in,
                              void* d_out, int out_size, void* d_ws, size_t ws_size,
                              hipStream_t stream) {
    const float* x    = (const float*)d_in[0];
    const float* Wx   = (const float*)d_in[1];
    const float* bx   = (const float*)d_in[2];
    const float* Wfx  = (const float*)d_in[3];
    const float* bfx  = (const float*)d_in[4];
    const float* Ws   = (const float*)d_in[5];
    const float* bs   = (const float*)d_in[6];
    const float* temp = (const float*)d_in[7];
    const float* Wq   = (const float*)d_in[8];
    const float* Wk   = (const float*)d_in[9];
    const float* Wv   = (const float*)d_in[10];
    const float* Wo   = (const float*)d_in[11];
    const float* Wout = (const float*)d_in[12];
    const float* bout = (const float*)d_in[13];

    const int N = in_sizes[0] / HID;

    char* p = (char*)d_ws;
    short* mid = (short*)p;           p += (size_t)N * 1024 * 2;       // fx | w (bf16)
    short* Wcat = (short*)p;          p += (size_t)1024 * 512 * 2;
    float* bias_cat = (float*)p;      p += 1024 * 4;
    float* tok_raw = (float*)p;       p += (size_t)NH * GG * DD * 4;   // contiguous with norm
    float* norm_ = (float*)p;         p += (size_t)NH * GG * 4;
    float* out_tok = (float*)p;       p += (size_t)NH * GG * DD * 4;
    short* Vbf = (short*)p;           p += (size_t)512 * 512 * 2;

    fold1_kernel<<<2048, 256, 0, stream>>>(Wx, bx, Wfx, bfx, Ws, bs, temp, Wcat, bias_cat);
    hipMemsetAsync(tok_raw, 0, (size_t)(NH * GG * DD + NH * GG) * 4, stream);

    const int R = (N + 127) / 128;
    const int slice = (R + 7) / 8;

    // GEMM1 (cast fused): C=8 col tiles, fused softmax on logits half
    gemm1_fused<<<8 * slice * 8, 256, 0, stream>>>(
        x, Wcat, bias_cat, mid, N, 3, R);

    // pool: split-K MFMA; chunk multiple of 32 (N=100000 is a multiple of 32)
    const int chunk = 544;                       // 17 k-steps per block
    dim3 g2((N + chunk - 1) / chunk, 8);
    pool_mfma<<<g2, 256, 0, stream>>>(mid, tok_raw, norm_, N, chunk);

    attn_kernel<<<8, 256, 0, stream>>>(tok_raw, norm_, Wq, Wk, Wv, Wo, out_tok);

    fold2_kernel<<<1024, 256, 0, stream>>>(out_tok, Wout, Vbf);

    // GEMM2: C=4 col tiles (A = w half of mid, bf16; output f32 + bout)
    gemm_bt<true, false><<<8 * slice * 4, 256, 0, stream>>>(
        mid + 512, 1024, Vbf, bout, d_out, HID, N, 512, 2, R);
}